// Round 1
// baseline (355.076 us; speedup 1.0000x reference)
//
#include <hip/hip_runtime.h>

#define BLOCK 256

// One thread processes 4 consecutive rows so that every global access is an
// aligned 16B vector op:
//   prnt/child: 3 floats/row -> 3 float4 per thread
//   eps_M:      9 floats/row -> 9 float4 per thread
//   beta/rels:  1 float4 / int4 per thread
//   outputs:    masks 1 float4, cp/alpha 3 float4 per thread
__global__ __launch_bounds__(BLOCK) void alpha_kernel(
    const float4* __restrict__ prnt4,
    const float4* __restrict__ child4,
    const float*  __restrict__ rel_mu,
    const float*  __restrict__ rel_sigma,
    const float4* __restrict__ eps4,
    const float4* __restrict__ beta4,
    const int4*   __restrict__ rels4,
    float4* __restrict__ out0,   // copy_mask       (N floats)
    float4* __restrict__ out1,   // child_probs2copy (3N floats)
    float4* __restrict__ out2,   // alpha_mask      (N floats)
    float4* __restrict__ out3,   // alpha           (3N floats)
    int ngroups, int nmu)
{
    __shared__ float smu[192];
    __shared__ float ssg[192];
    for (int i = threadIdx.x; i < nmu; i += BLOCK) {
        smu[i] = rel_mu[i];
        ssg[i] = rel_sigma[i];
    }
    __syncthreads();

    int t = blockIdx.x * BLOCK + threadIdx.x;
    if (t >= ngroups) return;

    float p[12], c[12], e[36];
    {
        float4 v;
        #pragma unroll
        for (int k = 0; k < 3; ++k) {
            v = prnt4[3 * t + k];
            p[4*k+0] = v.x; p[4*k+1] = v.y; p[4*k+2] = v.z; p[4*k+3] = v.w;
        }
        #pragma unroll
        for (int k = 0; k < 3; ++k) {
            v = child4[3 * t + k];
            c[4*k+0] = v.x; c[4*k+1] = v.y; c[4*k+2] = v.z; c[4*k+3] = v.w;
        }
        #pragma unroll
        for (int k = 0; k < 9; ++k) {
            v = eps4[9 * t + k];
            e[4*k+0] = v.x; e[4*k+1] = v.y; e[4*k+2] = v.z; e[4*k+3] = v.w;
        }
    }
    float4 btv = beta4[t];
    int4   rv  = rels4[t];
    float bq[4] = {btv.x, btv.y, btv.z, btv.w};
    int   rq[4] = {rv.x, rv.y, rv.z, rv.w};

    float o0[4], o2[4], o1[12], o3[12];

    #pragma unroll
    for (int q = 0; q < 4; ++q) {
        const float* pp = &p[3 * q];
        const float* cc = &c[3 * q];
        const float* ee = &e[9 * q];
        const float* mu = &smu[9 * rq[q]];
        const float* sg = &ssg[9 * rq[q]];

        // logits = (mu + sigma*eps) @ child
        float l[3];
        #pragma unroll
        for (int i = 0; i < 3; ++i) {
            float acc = 0.0f;
            #pragma unroll
            for (int j = 0; j < 3; ++j) {
                float m = fmaf(sg[3*i+j], ee[3*i+j], mu[3*i+j]);
                acc = fmaf(m, cc[j], acc);
            }
            l[i] = acc;
        }
        // softmax (3-wide)
        float mx = fmaxf(l[0], fmaxf(l[1], l[2]));
        float e0 = __expf(l[0] - mx), e1 = __expf(l[1] - mx), e2 = __expf(l[2] - mx);
        float einv = 1.0f / (e0 + e1 + e2);
        float cp0 = e0 * einv, cp1 = e1 * einv, cp2 = e2 * einv;

        float csum = cc[0] + cc[1] + cc[2];
        float psum = pp[0] + pp[1] + pp[2];
        bool cmask = (csum != 0.0f);
        bool copy  = cmask && (psum == 0.0f);
        bool amask = cmask && (psum != 0.0f);

        // _scale(prnt, cp)
        float z0 = fmaxf(0.01f, pp[0] + cp0);
        float z1 = fmaxf(0.01f, pp[1] + cp1);
        float z2 = fmaxf(0.01f, pp[2] + cp2);
        float zinv = 1.0f / (z0 + z1 + z2);
        z0 *= zinv; z1 *= zinv; z2 *= zinv;
        float ent = -(z0 * __logf(z0) + z1 * __logf(z1) + z2 * __logf(z2));
        float cosv = pp[0]*cp0 + pp[1]*cp1 + pp[2]*cp2;
        float np2 = pp[0]*pp[0] + pp[1]*pp[1] + pp[2]*pp[2];
        float nc2 = cp0*cp0 + cp1*cp1 + cp2*cp2;
        float npn = (np2 == 0.0f) ? 0.0f : sqrtf(np2);
        float ncn = (nc2 == 0.0f) ? 0.0f : sqrtf(nc2);
        float nrm = npn * ncn;
        nrm = (nrm == 0.0f) ? 1.0f : nrm;
        cosv = fmaxf(0.01f, cosv / nrm);
        float s = 42.0f * cosv / ent;

        float b = bq[q], ob = 1.0f - b;
        float a0 = fmaf(ob, pp[0], b * cp0) * s;
        float a1 = fmaf(ob, pp[1], b * cp1) * s;
        float a2 = fmaf(ob, pp[2], b * cp2) * s;

        o0[q] = copy  ? 1.0f : 0.0f;
        o2[q] = amask ? 1.0f : 0.0f;
        o1[3*q+0] = copy ? cp0 : 0.0f;
        o1[3*q+1] = copy ? cp1 : 0.0f;
        o1[3*q+2] = copy ? cp2 : 0.0f;
        o3[3*q+0] = amask ? a0 : 0.0f;
        o3[3*q+1] = amask ? a1 : 0.0f;
        o3[3*q+2] = amask ? a2 : 0.0f;
    }

    out0[t] = make_float4(o0[0], o0[1], o0[2], o0[3]);
    out2[t] = make_float4(o2[0], o2[1], o2[2], o2[3]);
    #pragma unroll
    for (int k = 0; k < 3; ++k) {
        out1[3*t+k] = make_float4(o1[4*k+0], o1[4*k+1], o1[4*k+2], o1[4*k+3]);
        out3[3*t+k] = make_float4(o3[4*k+0], o3[4*k+1], o3[4*k+2], o3[4*k+3]);
    }
}

extern "C" void kernel_launch(void* const* d_in, const int* in_sizes, int n_in,
                              void* d_out, int out_size, void* d_ws, size_t ws_size,
                              hipStream_t stream)
{
    const float* prnt      = (const float*)d_in[0];
    const float* child     = (const float*)d_in[1];
    const float* rel_mu    = (const float*)d_in[2];
    const float* rel_sigma = (const float*)d_in[3];
    const float* eps       = (const float*)d_in[4];
    const float* beta      = (const float*)d_in[5];
    const int*   rels      = (const int*)d_in[6];

    const int N = in_sizes[5];          // 4,000,000 (divisible by 4)
    const int ngroups = N / 4;
    const int nmu = in_sizes[2];        // 180

    float* out  = (float*)d_out;
    float* out0 = out;                      // copy_mask        [N]
    float* out1 = out + (size_t)N;          // child_probs2copy [N,3]
    float* out2 = out + (size_t)4 * N;      // alpha_mask       [N]
    float* out3 = out + (size_t)5 * N;      // alpha            [N,3]

    int blocks = (ngroups + BLOCK - 1) / BLOCK;
    alpha_kernel<<<blocks, BLOCK, 0, stream>>>(
        (const float4*)prnt, (const float4*)child, rel_mu, rel_sigma,
        (const float4*)eps, (const float4*)beta, (const int4*)rels,
        (float4*)out0, (float4*)out1, (float4*)out2, (float4*)out3,
        ngroups, nmu);
}

// Round 2
// 335.308 us; speedup vs baseline: 1.0590x; 1.0590x over previous
//
#include <hip/hip_runtime.h>

#define BLOCK 256
#define ROWS  512                 // rows per block (2 per thread)
#define PCF4  (ROWS * 3 / 4)      // 384 float4 per block for prnt/child
#define EPSF4 (ROWS * 9 / 4)      // 1152 float4 per block for eps

// All strided row-major [N,3]/[N,3,3] traffic goes through LDS so that every
// global access is unit-stride float4 across the wave:
//   loads : prnt/child/eps  -> cooperative f4 loads into LDS, per-row reads from LDS
//   stores: out1/out3       -> per-row writes into LDS, cooperative f4 stores
//   beta/rels/out0/out2     -> naturally coalesced (float2/int2 per thread), direct
__global__ __launch_bounds__(BLOCK) void alpha_kernel(
    const float4* __restrict__ prnt4,
    const float4* __restrict__ child4,
    const float*  __restrict__ rel_mu,
    const float*  __restrict__ rel_sigma,
    const float4* __restrict__ eps4,
    const float2* __restrict__ beta2,
    const int2*   __restrict__ rels2,
    float2* __restrict__ out0,   // copy_mask        (N floats)
    float4* __restrict__ out1,   // child_probs2copy (3N floats)
    float2* __restrict__ out2,   // alpha_mask       (N floats)
    float4* __restrict__ out3,   // alpha            (3N floats)
    int n_rows, int nmu)
{
    __shared__ float4 s_p[PCF4];
    __shared__ float4 s_c[PCF4];
    __shared__ float4 s_e[EPSF4];
    __shared__ float  smu[192];
    __shared__ float  ssg[192];

    for (int i = threadIdx.x; i < nmu; i += BLOCK) {
        smu[i] = rel_mu[i];
        ssg[i] = rel_sigma[i];
    }

    const int  b         = blockIdx.x;
    const long rows_base = (long)b * ROWS;
    const int  rows_here = min(ROWS, (int)(n_rows - rows_base));
    const int  pcf4_here  = rows_here * 3 / 4;
    const int  epsf4_here = rows_here * 9 / 4;

    const float4* gp = prnt4  + (size_t)b * PCF4;
    const float4* gc = child4 + (size_t)b * PCF4;
    const float4* ge = eps4   + (size_t)b * EPSF4;

    for (int i = threadIdx.x; i < pcf4_here; i += BLOCK) {
        s_p[i] = gp[i];
        s_c[i] = gc[i];
    }
    for (int i = threadIdx.x; i < epsf4_here; i += BLOCK) {
        s_e[i] = ge[i];
    }
    __syncthreads();

    const int  lt     = threadIdx.x;
    const bool active = (lt < rows_here / 2);

    float o1[6], o3[6];
    float2 m0, m2;

    if (active) {
        const float* pf = (const float*)s_p;
        const float* cf = (const float*)s_c;
        const float* ef = (const float*)s_e;

        float p[6], c[6], e[18];
        #pragma unroll
        for (int k = 0; k < 6; ++k)  p[k] = pf[6 * lt + k];
        #pragma unroll
        for (int k = 0; k < 6; ++k)  c[k] = cf[6 * lt + k];
        #pragma unroll
        for (int k = 0; k < 18; ++k) e[k] = ef[18 * lt + k];

        float2 bt = beta2[rows_base / 2 + lt];
        int2   rl = rels2[rows_base / 2 + lt];
        float bq[2] = {bt.x, bt.y};
        int   rq[2] = {rl.x, rl.y};

        float mo0[2], mo2[2];

        #pragma unroll
        for (int q = 0; q < 2; ++q) {
            const float* pp = &p[3 * q];
            const float* cc = &c[3 * q];
            const float* ee = &e[9 * q];
            const float* mu = &smu[9 * rq[q]];
            const float* sg = &ssg[9 * rq[q]];

            // logits = (mu + sigma*eps) @ child
            float l[3];
            #pragma unroll
            for (int i = 0; i < 3; ++i) {
                float acc = 0.0f;
                #pragma unroll
                for (int j = 0; j < 3; ++j) {
                    float m = fmaf(sg[3 * i + j], ee[3 * i + j], mu[3 * i + j]);
                    acc = fmaf(m, cc[j], acc);
                }
                l[i] = acc;
            }
            // softmax (3-wide)
            float mx = fmaxf(l[0], fmaxf(l[1], l[2]));
            float e0 = __expf(l[0] - mx), e1 = __expf(l[1] - mx), e2 = __expf(l[2] - mx);
            float einv = 1.0f / (e0 + e1 + e2);
            float cp0 = e0 * einv, cp1 = e1 * einv, cp2 = e2 * einv;

            float csum = cc[0] + cc[1] + cc[2];
            float psum = pp[0] + pp[1] + pp[2];
            bool cmask = (csum != 0.0f);
            bool copy  = cmask && (psum == 0.0f);
            bool amask = cmask && (psum != 0.0f);

            // _scale(prnt, cp)
            float z0 = fmaxf(0.01f, pp[0] + cp0);
            float z1 = fmaxf(0.01f, pp[1] + cp1);
            float z2 = fmaxf(0.01f, pp[2] + cp2);
            float zinv = 1.0f / (z0 + z1 + z2);
            z0 *= zinv; z1 *= zinv; z2 *= zinv;
            float ent = -(z0 * __logf(z0) + z1 * __logf(z1) + z2 * __logf(z2));
            float cosv = pp[0] * cp0 + pp[1] * cp1 + pp[2] * cp2;
            float np2 = pp[0] * pp[0] + pp[1] * pp[1] + pp[2] * pp[2];
            float nc2 = cp0 * cp0 + cp1 * cp1 + cp2 * cp2;
            float npn = (np2 == 0.0f) ? 0.0f : sqrtf(np2);
            float ncn = (nc2 == 0.0f) ? 0.0f : sqrtf(nc2);
            float nrm = npn * ncn;
            nrm = (nrm == 0.0f) ? 1.0f : nrm;
            cosv = fmaxf(0.01f, cosv / nrm);
            float s = 42.0f * cosv / ent;

            float bb = bq[q], ob = 1.0f - bb;
            float a0 = fmaf(ob, pp[0], bb * cp0) * s;
            float a1 = fmaf(ob, pp[1], bb * cp1) * s;
            float a2 = fmaf(ob, pp[2], bb * cp2) * s;

            mo0[q] = copy  ? 1.0f : 0.0f;
            mo2[q] = amask ? 1.0f : 0.0f;
            o1[3 * q + 0] = copy ? cp0 : 0.0f;
            o1[3 * q + 1] = copy ? cp1 : 0.0f;
            o1[3 * q + 2] = copy ? cp2 : 0.0f;
            o3[3 * q + 0] = amask ? a0 : 0.0f;
            o3[3 * q + 1] = amask ? a1 : 0.0f;
            o3[3 * q + 2] = amask ? a2 : 0.0f;
        }
        m0 = make_float2(mo0[0], mo0[1]);
        m2 = make_float2(mo2[0], mo2[1]);
    }

    // All LDS input reads complete -> safe to reuse s_p/s_c for outputs.
    __syncthreads();

    if (active) {
        float* of1 = (float*)s_p;
        float* of3 = (float*)s_c;
        #pragma unroll
        for (int k = 0; k < 6; ++k) of1[6 * lt + k] = o1[k];
        #pragma unroll
        for (int k = 0; k < 6; ++k) of3[6 * lt + k] = o3[k];
        out0[rows_base / 2 + lt] = m0;
        out2[rows_base / 2 + lt] = m2;
    }
    __syncthreads();

    float4* g1 = out1 + (size_t)b * PCF4;
    float4* g3 = out3 + (size_t)b * PCF4;
    for (int i = threadIdx.x; i < pcf4_here; i += BLOCK) {
        g1[i] = s_p[i];
        g3[i] = s_c[i];
    }
}

extern "C" void kernel_launch(void* const* d_in, const int* in_sizes, int n_in,
                              void* d_out, int out_size, void* d_ws, size_t ws_size,
                              hipStream_t stream)
{
    const float* prnt      = (const float*)d_in[0];
    const float* child     = (const float*)d_in[1];
    const float* rel_mu    = (const float*)d_in[2];
    const float* rel_sigma = (const float*)d_in[3];
    const float* eps       = (const float*)d_in[4];
    const float* beta      = (const float*)d_in[5];
    const int*   rels      = (const int*)d_in[6];

    const int N   = in_sizes[5];   // 4,000,000
    const int nmu = in_sizes[2];   // 180

    float* out  = (float*)d_out;
    float* out0 = out;                      // copy_mask        [N]
    float* out1 = out + (size_t)N;          // child_probs2copy [N,3]
    float* out2 = out + (size_t)4 * N;      // alpha_mask       [N]
    float* out3 = out + (size_t)5 * N;      // alpha            [N,3]

    int blocks = (N + ROWS - 1) / ROWS;
    alpha_kernel<<<blocks, BLOCK, 0, stream>>>(
        (const float4*)prnt, (const float4*)child, rel_mu, rel_sigma,
        (const float4*)eps, (const float2*)beta, (const int2*)rels,
        (float2*)out0, (float4*)out1, (float2*)out2, (float4*)out3,
        N, nmu);
}

// Round 4
// 330.528 us; speedup vs baseline: 1.0743x; 1.0145x over previous
//
#include <hip/hip_runtime.h>

#define BLOCK 256
#define ROWS  512                 // rows per block (2 per thread)
#define PCF4  (ROWS * 3 / 4)      // 384 float4 per block for prnt/child
#define EPSF4 (ROWS * 9 / 4)      // 1152 float4 per block for eps

typedef const __attribute__((address_space(1))) void* gas1_t;
typedef __attribute__((address_space(3)))       void* las3_t;

// Async direct-to-LDS 16B load: lane L of the wave loads g[L] (1KB/wave per
// issue) into LDS at (wave-uniform) l + L*16. Drained by __syncthreads()
// (compiler emits s_waitcnt vmcnt(0) before s_barrier).
__device__ __forceinline__ void ld_lds16(const float4* g, float4* l) {
    __builtin_amdgcn_global_load_lds((gas1_t)(const void*)g, (las3_t)(void*)l, 16, 0, 0);
}

__global__ __launch_bounds__(BLOCK) void alpha_kernel(
    const float4* __restrict__ prnt4,
    const float4* __restrict__ child4,
    const float*  __restrict__ rel_mu,
    const float*  __restrict__ rel_sigma,
    const float4* __restrict__ eps4,
    const float2* __restrict__ beta2,
    const int2*   __restrict__ rels2,
    float2* __restrict__ out0,   // copy_mask        (N floats)
    float4* __restrict__ out1,   // child_probs2copy (3N floats)
    float2* __restrict__ out2,   // alpha_mask       (N floats)
    float4* __restrict__ out3,   // alpha            (3N floats)
    int n_rows, int nmu)
{
    __shared__ float4 s_p[PCF4];
    __shared__ float4 s_c[PCF4];
    __shared__ float4 s_e[EPSF4];
    __shared__ float  smu[192];
    __shared__ float  ssg[192];

    const int  tid       = threadIdx.x;
    const int  lane      = tid & 63;
    const int  wv        = tid >> 6;          // 4 waves per block
    const int  b         = blockIdx.x;
    const long rows_base = (long)b * ROWS;
    const int  rows_here = min(ROWS, (int)(n_rows - rows_base));
    const bool full      = (rows_here == ROWS);

    const float4* gp = prnt4  + (size_t)b * PCF4;
    const float4* gc = child4 + (size_t)b * PCF4;
    const float4* ge = eps4   + (size_t)b * EPSF4;

    // --- scalar loads issued first so their waitcnt doesn't drain the async queue
    float rmu = 0.0f, rsg = 0.0f;
    const bool has_mu = (tid < nmu);
    if (has_mu) { rmu = rel_mu[tid]; rsg = rel_sigma[tid]; }

    const bool active = (tid < rows_here / 2);
    float2 bt = make_float2(0.0f, 0.0f);
    int2   rl = make_int2(0, 0);
    if (active) {
        bt = beta2[rows_base / 2 + tid];
        rl = rels2[rows_base / 2 + tid];
    }

    // --- async global->LDS staging, 64-float4 (1KB) chunks per wave issue
    if (full) {
        for (int c = wv; c < PCF4 / 64; c += 4) {          // 6 chunks each
            ld_lds16(gp + (c << 6) + lane, s_p + (c << 6));
            ld_lds16(gc + (c << 6) + lane, s_c + (c << 6));
        }
        for (int c = wv; c < EPSF4 / 64; c += 4) {         // 18 chunks
            ld_lds16(ge + (c << 6) + lane, s_e + (c << 6));
        }
    } else {
        const int pcf4_here  = rows_here * 3 / 4;
        const int epsf4_here = rows_here * 9 / 4;
        const int pc_chunks  = pcf4_here >> 6;
        const int eps_chunks = epsf4_here >> 6;
        for (int c = wv; c < pc_chunks; c += 4) {
            ld_lds16(gp + (c << 6) + lane, s_p + (c << 6));
            ld_lds16(gc + (c << 6) + lane, s_c + (c << 6));
        }
        for (int c = wv; c < eps_chunks; c += 4) {
            ld_lds16(ge + (c << 6) + lane, s_e + (c << 6));
        }
        // remainders (none for N=4M, kept for generality)
        for (int i = (pc_chunks << 6) + tid; i < pcf4_here; i += BLOCK) {
            s_p[i] = gp[i];
            s_c[i] = gc[i];
        }
        for (int i = (eps_chunks << 6) + tid; i < epsf4_here; i += BLOCK) {
            s_e[i] = ge[i];
        }
    }

    if (has_mu) { smu[tid] = rmu; ssg[tid] = rsg; }
    __syncthreads();

    float o1[6], o3[6];
    float2 m0 = make_float2(0.0f, 0.0f), m2 = make_float2(0.0f, 0.0f);

    if (active) {
        const float* pf = (const float*)s_p;
        const float* cf = (const float*)s_c;
        const float* ef = (const float*)s_e;

        float p[6], c[6], e[18];
        #pragma unroll
        for (int k = 0; k < 6; ++k)  p[k] = pf[6 * tid + k];
        #pragma unroll
        for (int k = 0; k < 6; ++k)  c[k] = cf[6 * tid + k];
        #pragma unroll
        for (int k = 0; k < 18; ++k) e[k] = ef[18 * tid + k];

        float bq[2] = {bt.x, bt.y};
        int   rq[2] = {rl.x, rl.y};
        float mo0[2], mo2[2];

        #pragma unroll
        for (int q = 0; q < 2; ++q) {
            const float* pp = &p[3 * q];
            const float* cc = &c[3 * q];
            const float* ee = &e[9 * q];
            const float* mu = &smu[9 * rq[q]];
            const float* sg = &ssg[9 * rq[q]];

            // logits = (mu + sigma*eps) @ child
            float l[3];
            #pragma unroll
            for (int i = 0; i < 3; ++i) {
                float acc = 0.0f;
                #pragma unroll
                for (int j = 0; j < 3; ++j) {
                    float m = fmaf(sg[3 * i + j], ee[3 * i + j], mu[3 * i + j]);
                    acc = fmaf(m, cc[j], acc);
                }
                l[i] = acc;
            }
            // softmax (3-wide)
            float mx = fmaxf(l[0], fmaxf(l[1], l[2]));
            float e0 = __expf(l[0] - mx), e1 = __expf(l[1] - mx), e2 = __expf(l[2] - mx);
            float einv = 1.0f / (e0 + e1 + e2);
            float cp0 = e0 * einv, cp1 = e1 * einv, cp2 = e2 * einv;

            float csum = cc[0] + cc[1] + cc[2];
            float psum = pp[0] + pp[1] + pp[2];
            bool cmask = (csum != 0.0f);
            bool copy  = cmask && (psum == 0.0f);
            bool amask = cmask && (psum != 0.0f);

            // _scale(prnt, cp)
            float z0 = fmaxf(0.01f, pp[0] + cp0);
            float z1 = fmaxf(0.01f, pp[1] + cp1);
            float z2 = fmaxf(0.01f, pp[2] + cp2);
            float zinv = 1.0f / (z0 + z1 + z2);
            z0 *= zinv; z1 *= zinv; z2 *= zinv;
            float ent = -(z0 * __logf(z0) + z1 * __logf(z1) + z2 * __logf(z2));
            float cosv = pp[0] * cp0 + pp[1] * cp1 + pp[2] * cp2;
            float np2 = pp[0] * pp[0] + pp[1] * pp[1] + pp[2] * pp[2];
            float nc2 = cp0 * cp0 + cp1 * cp1 + cp2 * cp2;
            float npn = (np2 == 0.0f) ? 0.0f : sqrtf(np2);
            float ncn = (nc2 == 0.0f) ? 0.0f : sqrtf(nc2);
            float nrm = npn * ncn;
            nrm = (nrm == 0.0f) ? 1.0f : nrm;
            cosv = fmaxf(0.01f, cosv / nrm);
            float s = 42.0f * cosv / ent;

            float bb = bq[q], ob = 1.0f - bb;
            float a0 = fmaf(ob, pp[0], bb * cp0) * s;
            float a1 = fmaf(ob, pp[1], bb * cp1) * s;
            float a2 = fmaf(ob, pp[2], bb * cp2) * s;

            mo0[q] = copy  ? 1.0f : 0.0f;
            mo2[q] = amask ? 1.0f : 0.0f;
            o1[3 * q + 0] = copy ? cp0 : 0.0f;
            o1[3 * q + 1] = copy ? cp1 : 0.0f;
            o1[3 * q + 2] = copy ? cp2 : 0.0f;
            o3[3 * q + 0] = amask ? a0 : 0.0f;
            o3[3 * q + 1] = amask ? a1 : 0.0f;
            o3[3 * q + 2] = amask ? a2 : 0.0f;
        }
        m0 = make_float2(mo0[0], mo0[1]);
        m2 = make_float2(mo2[0], mo2[1]);
    }

    // All LDS input reads complete -> safe to reuse s_p/s_c for outputs.
    __syncthreads();

    if (active) {
        float* of1 = (float*)s_p;
        float* of3 = (float*)s_c;
        #pragma unroll
        for (int k = 0; k < 6; ++k) of1[6 * tid + k] = o1[k];
        #pragma unroll
        for (int k = 0; k < 6; ++k) of3[6 * tid + k] = o3[k];
        out0[rows_base / 2 + tid] = m0;
        out2[rows_base / 2 + tid] = m2;
    }
    __syncthreads();

    float4* g1 = out1 + (size_t)b * PCF4;
    float4* g3 = out3 + (size_t)b * PCF4;
    const int pcf4_here = rows_here * 3 / 4;
    for (int i = tid; i < pcf4_here; i += BLOCK) {
        g1[i] = s_p[i];
        g3[i] = s_c[i];
    }
}

extern "C" void kernel_launch(void* const* d_in, const int* in_sizes, int n_in,
                              void* d_out, int out_size, void* d_ws, size_t ws_size,
                              hipStream_t stream)
{
    const float* prnt      = (const float*)d_in[0];
    const float* child     = (const float*)d_in[1];
    const float* rel_mu    = (const float*)d_in[2];
    const float* rel_sigma = (const float*)d_in[3];
    const float* eps       = (const float*)d_in[4];
    const float* beta      = (const float*)d_in[5];
    const int*   rels      = (const int*)d_in[6];

    const int N   = in_sizes[5];   // 4,000,000
    const int nmu = in_sizes[2];   // 180

    float* out  = (float*)d_out;
    float* out0 = out;                      // copy_mask        [N]
    float* out1 = out + (size_t)N;          // child_probs2copy [N,3]
    float* out2 = out + (size_t)4 * N;      // alpha_mask       [N]
    float* out3 = out + (size_t)5 * N;      // alpha            [N,3]

    int blocks = (N + ROWS - 1) / ROWS;
    alpha_kernel<<<blocks, BLOCK, 0, stream>>>(
        (const float4*)prnt, (const float4*)child, rel_mu, rel_sigma,
        (const float4*)eps, (const float2*)beta, (const int2*)rels,
        (float2*)out0, (float4*)out1, (float2*)out2, (float4*)out3,
        N, nmu);
}